// Round 17
// baseline (557.836 us; speedup 1.0000x reference)
//
#include <hip/hip_runtime.h>
#include <math.h>

constexpr int Nn   = 50000;
constexpr int Ee   = 800000;
constexpr int Bb   = 128;
constexpr int INF  = 15;
constexpr int HID  = 256;
constexpr int OUTF = 128;

constexpr int NCB   = (Nn + 255) / 256;   // 196 coarse buckets (dst>>8)
constexpr int CHUNK = 4096;
constexpr int NB1   = (Ee + CHUNK - 1) / CHUNK;  // 196 sort blocks
constexpr int SCANN = NCB * NB1;          // 38416

// pipeline stage boundaries (multiples of 32)
constexpr int S1 = 12512, S2 = 25024, S3 = 37536;

typedef __attribute__((ext_vector_type(8))) __bf16 bf16x8;
typedef __attribute__((ext_vector_type(4))) float  f32x4;

// gelu(v) = 0.5 v (1 + erf(v/sqrt2)); erf via A&S 7.1.26 (max err 1.5e-7, sub-bf16-ulp).
__device__ __forceinline__ float gelu_f(float v) {
    float s = fabsf(v) * 0.7071067811865475f;
    float t = __builtin_amdgcn_rcpf(fmaf(0.3275911f, s, 1.0f));
    float p = fmaf(fmaf(fmaf(fmaf(1.061405429f, t, -1.453152027f),
                             t, 1.421413741f), t, -0.284496736f), t, 0.254829592f) * t;
    float e = __expf(-s * s);
    float er = copysignf(1.0f - p * e, v);
    return 0.5f * v * (1.0f + er);
}

__device__ __forceinline__ unsigned short f2bf(float f) {
    union { float f; unsigned int u; } v; v.f = f;
    unsigned int r = v.u + 0x7fffu + ((v.u >> 16) & 1u);   // RNE
    return (unsigned short)(r >> 16);
}

__device__ __forceinline__ float bflo(unsigned int p) { return __uint_as_float(p << 16); }
__device__ __forceinline__ float bfhi(unsigned int p) { return __uint_as_float(p & 0xffff0000u); }

// ---------------- CSR build: two-level counting sort (LDS atomics only) ----------------

__global__ void k_sortA(const int* __restrict__ dst, int* __restrict__ Gcnt) {
    __shared__ int cnt[NCB];
    int tid = threadIdx.x, blk = blockIdx.x;
    for (int i = tid; i < NCB; i += 256) cnt[i] = 0;
    __syncthreads();
    int base = blk * CHUNK;
    for (int i = 0; i < CHUNK; i += 256) {
        int e = base + i + tid;
        if (e < Ee) atomicAdd(&cnt[dst[e] >> 8], 1);
    }
    __syncthreads();
    for (int i = tid; i < NCB; i += 256) Gcnt[i * NB1 + blk] = cnt[i];
}

__global__ void k_gscan_partial(const int* __restrict__ in, int* __restrict__ partial, int n) {
    __shared__ int s[256];
    int tid = threadIdx.x, i = blockIdx.x * 256 + tid;
    s[tid] = (i < n) ? in[i] : 0;
    __syncthreads();
    for (int off = 128; off; off >>= 1) {
        if (tid < off) s[tid] += s[tid + off];
        __syncthreads();
    }
    if (tid == 0) partial[blockIdx.x] = s[0];
}

__global__ void k_gscan_mid(int* __restrict__ partial, int nb) {
    __shared__ int s[256];
    int tid = threadIdx.x;
    int v = (tid < nb) ? partial[tid] : 0;
    s[tid] = v;
    __syncthreads();
    for (int off = 1; off < 256; off <<= 1) {
        int t = (tid >= off) ? s[tid - off] : 0;
        __syncthreads();
        s[tid] += t;
        __syncthreads();
    }
    if (tid < nb) partial[tid] = s[tid] - v;
}

__global__ void k_gscan_final(const int* __restrict__ in, const int* __restrict__ partial,
                              int* __restrict__ out, int n) {
    __shared__ int s[256];
    int tid = threadIdx.x, i = blockIdx.x * 256 + tid;
    int v = (i < n) ? in[i] : 0;
    s[tid] = v;
    __syncthreads();
    for (int off = 1; off < 256; off <<= 1) {
        int t = (tid >= off) ? s[tid - off] : 0;
        __syncthreads();
        s[tid] += t;
        __syncthreads();
    }
    if (i < n) out[i] = s[tid] - v + partial[blockIdx.x];
}

__global__ void k_sortC(const int* __restrict__ dst, const int* __restrict__ srcv,
                        const int* __restrict__ Goff, unsigned int* __restrict__ pairs) {
    __shared__ int cur[NCB];
    int tid = threadIdx.x, blk = blockIdx.x;
    for (int i = tid; i < NCB; i += 256) cur[i] = Goff[i * NB1 + blk];
    __syncthreads();
    int base = blk * CHUNK;
    for (int i = 0; i < CHUNK; i += 256) {
        int e = base + i + tid;
        if (e < Ee) {
            int d = dst[e];
            int p = atomicAdd(&cur[d >> 8], 1);
            pairs[p] = ((unsigned int)(d & 255) << 16) | (unsigned int)srcv[e];
        }
    }
}

__global__ void k_sortD(const unsigned int* __restrict__ pairs, const int* __restrict__ Goff,
                        int* __restrict__ offs, int* __restrict__ srcs, float* __restrict__ invc) {
    __shared__ int fcnt[256];
    __shared__ int fbase[256];
    __shared__ int s[256];
    int tid = threadIdx.x, cb = blockIdx.x;
    int cbase = Goff[cb * NB1];
    int cend = (cb + 1 < NCB) ? Goff[(cb + 1) * NB1] : Ee;
    fcnt[tid] = 0;
    __syncthreads();
    for (int e = cbase + tid; e < cend; e += 256)
        atomicAdd(&fcnt[pairs[e] >> 16], 1);
    __syncthreads();
    int v = fcnt[tid];
    s[tid] = v;
    __syncthreads();
    for (int off = 1; off < 256; off <<= 1) {
        int t = (tid >= off) ? s[tid - off] : 0;
        __syncthreads();
        s[tid] += t;
        __syncthreads();
    }
    fbase[tid] = cbase + s[tid] - v;
    int node = cb * 256 + tid;
    if (node < Nn) {
        offs[node] = fbase[tid];
        invc[node] = 1.0f / (float)(v > 1 ? v : 1);
    }
    __syncthreads();
    fcnt[tid] = fbase[tid];
    __syncthreads();
    for (int e = cbase + tid; e < cend; e += 256) {
        unsigned int pv = pairs[e];
        int p = atomicAdd(&fcnt[pv >> 16], 1);
        srcs[p] = (int)(pv & 0xFFFFu);
    }
}

__global__ void k_bsearch(const int* __restrict__ batch, int* __restrict__ boff,
                          int* __restrict__ offs) {
    int b = threadIdx.x;
    if (b <= Bb) {
        int lo = 0, hi = Nn;
        while (lo < hi) {
            int mid = (lo + hi) >> 1;
            if (batch[mid] < b) lo = mid + 1; else hi = mid;
        }
        boff[b] = lo;
    }
    if (b == 0) offs[Nn] = Ee;
}

// ---------------- weight prep ----------------

template <int NOUT>
__global__ void k_prepW(const float* __restrict__ Wl, const float* __restrict__ Wr,
                        uint4* __restrict__ outw) {
    constexpr int NT = NOUT / 16;
    int G = blockIdx.x * 256 + threadIdx.x;
    int per = 2 * NT * 64;
    int S = G / per, rem = G % per;
    int lane = rem & 63, sT = rem >> 6;
    int s = sT / NT, T = sT % NT;
    int q = lane >> 4, m = lane & 15;
    int k0 = S * 64 + s * 32 + q * 8;
    int nc = T * 16 + m;
    union { uint4 u; unsigned short h[8]; } pk;
#pragma unroll
    for (int j = 0; j < 8; j++) {
        int kk = k0 + j;
        float wv = (kk < 256) ? Wl[kk * NOUT + nc] : Wr[(kk - 256) * NOUT + nc];
        pk.h[j] = f2bf(wv);
    }
    outw[G] = pk.u;
}

__global__ void k_prepW1(const float* __restrict__ Wl, const float* __restrict__ Wr,
                         uint4* __restrict__ outw) {
    int G = blockIdx.x * 256 + threadIdx.x;   // 0..1023
    int T = G >> 6, lane = G & 63;
    int q = lane >> 4, m = lane & 15;
    int nc = T * 16 + m;
    union { uint4 u; unsigned short h[8]; } pk;
#pragma unroll
    for (int j = 0; j < 8; j++) {
        int k = q * 8 + j;
        float wv;
        if (k < 15)       wv = Wl[k * HID + nc];
        else if (k == 15) wv = 0.0f;
        else if (k < 31)  wv = Wr[(k - 16) * HID + nc];
        else              wv = 0.0f;
        pk.h[j] = f2bf(wv);
    }
    outw[G] = pk.u;
}

// ---------------- layer-1 A build ----------------

__global__ void k_prep1(const float* __restrict__ x, const int* __restrict__ offs,
                        const int* __restrict__ srcs, const float* __restrict__ invc,
                        unsigned short* __restrict__ A1) {
    int node = blockIdx.x * 16 + (threadIdx.x >> 4);
    int f = threadIdx.x & 15;
    int s0 = offs[node], s1 = offs[node + 1];
    float acc = 0.0f;
    for (int i = s0; i < s1; i++) {
        int s = srcs[i];
        if (f < 15) acc += x[s * INF + f];
    }
    unsigned short mv = (f < 15) ? f2bf(acc * invc[node]) : (unsigned short)0;
    unsigned short xv = (f < 15) ? f2bf(x[(size_t)node * INF + f]) : (unsigned short)0;
    A1[(size_t)node * 32 + f] = mv;
    A1[(size_t)node * 32 + 16 + f] = xv;
}

// ---------------- shared device bodies ----------------

__device__ __forceinline__ void acc8(float* a, uint4 v) {
    a[0] += bflo(v.x); a[1] += bfhi(v.x);
    a[2] += bflo(v.y); a[3] += bfhi(v.y);
    a[4] += bflo(v.z); a[5] += bfhi(v.z);
    a[6] += bflo(v.w); a[7] += bfhi(v.w);
}

// one wave aggregates one node (verbatim R14/R16 math)
__device__ __forceinline__ void agg_node(const uint4* __restrict__ h4,
                                         const int* __restrict__ offs,
                                         const int* __restrict__ srcs,
                                         const float* __restrict__ invc,
                                         uint4* __restrict__ mean4,
                                         int node, int lane) {
    int sub = lane >> 5, q = lane & 31;
    int s0 = offs[node], s1 = offs[node + 1];
    int deg = s1 - s0;
    int dcap = deg < 64 ? deg : 64;
    int myidx = (lane < deg) ? srcs[s0 + lane] : 0;
    float a[8] = {};
    int i = 0;
    for (; i + 16 <= dcap; i += 16) {
        int sA = __shfl(myidx, i + sub);
        int sB = __shfl(myidx, i + 2 + sub);
        int sC = __shfl(myidx, i + 4 + sub);
        int sD = __shfl(myidx, i + 6 + sub);
        int sE = __shfl(myidx, i + 8 + sub);
        int sF = __shfl(myidx, i + 10 + sub);
        int sG = __shfl(myidx, i + 12 + sub);
        int sH = __shfl(myidx, i + 14 + sub);
        uint4 vA = h4[(size_t)sA * 32 + q];
        uint4 vB = h4[(size_t)sB * 32 + q];
        uint4 vC = h4[(size_t)sC * 32 + q];
        uint4 vD = h4[(size_t)sD * 32 + q];
        uint4 vE = h4[(size_t)sE * 32 + q];
        uint4 vF = h4[(size_t)sF * 32 + q];
        uint4 vG = h4[(size_t)sG * 32 + q];
        uint4 vH = h4[(size_t)sH * 32 + q];
        acc8(a, vA); acc8(a, vB); acc8(a, vC); acc8(a, vD);
        acc8(a, vE); acc8(a, vF); acc8(a, vG); acc8(a, vH);
    }
    if (i + 8 <= dcap) {
        int sA = __shfl(myidx, i + sub);
        int sB = __shfl(myidx, i + 2 + sub);
        int sC = __shfl(myidx, i + 4 + sub);
        int sD = __shfl(myidx, i + 6 + sub);
        uint4 vA = h4[(size_t)sA * 32 + q];
        uint4 vB = h4[(size_t)sB * 32 + q];
        uint4 vC = h4[(size_t)sC * 32 + q];
        uint4 vD = h4[(size_t)sD * 32 + q];
        acc8(a, vA); acc8(a, vB); acc8(a, vC); acc8(a, vD);
        i += 8;
    }
    if (i + 4 <= dcap) {
        int sA = __shfl(myidx, i + sub);
        int sB = __shfl(myidx, i + 2 + sub);
        uint4 vA = h4[(size_t)sA * 32 + q];
        uint4 vB = h4[(size_t)sB * 32 + q];
        acc8(a, vA); acc8(a, vB);
        i += 4;
    }
    if (i + 2 <= dcap) {
        int sA = __shfl(myidx, i + sub);
        uint4 vA = h4[(size_t)sA * 32 + q];
        acc8(a, vA);
        i += 2;
    }
    if (i < dcap && sub == 0) {
        int sA = __shfl(myidx, i);
        uint4 vA = h4[(size_t)sA * 32 + q];
        acc8(a, vA);
    }
    for (int j = 64; j + 1 < deg; j += 2) {
        int s = srcs[s0 + j + sub];
        uint4 v = h4[(size_t)s * 32 + q];
        acc8(a, v);
    }
    if (deg > 64 && ((deg - 64) & 1) && sub == 0) {
        int s = srcs[s1 - 1];
        uint4 v = h4[(size_t)s * 32 + q];
        acc8(a, v);
    }
#pragma unroll
    for (int j = 0; j < 8; j++) a[j] += __shfl_xor(a[j], 32);
    if (sub == 0) {
        float ic = invc[node];
        uint4 o;
        o.x = (unsigned int)f2bf(a[0] * ic) | ((unsigned int)f2bf(a[1] * ic) << 16);
        o.y = (unsigned int)f2bf(a[2] * ic) | ((unsigned int)f2bf(a[3] * ic) << 16);
        o.z = (unsigned int)f2bf(a[4] * ic) | ((unsigned int)f2bf(a[5] * ic) << 16);
        o.w = (unsigned int)f2bf(a[6] * ic) | ((unsigned int)f2bf(a[7] * ic) << 16);
        mean4[(size_t)node * 32 + q] = o;
    }
}

// ---------------- k_mix: agg blocks + M=32 GEMM blocks in one grid ----------------
// blocks [0, aggBlocks): aggregate nodes [aggN0, aggN1) (4 nodes/block).
// blocks [aggBlocks, ...): R14-proven M=32 GEMM for rows [gemmR0, gemmR1).
// Chunked pipeline across launches: GEMM chunk c-1 overlaps agg chunk c.

template <int NOUT, bool F32OUT>
__global__ __launch_bounds__(256) void k_mix(
    const unsigned short* __restrict__ Ah,
    const int* __restrict__ offs, const int* __restrict__ srcs,
    const float* __restrict__ invc,
    unsigned short* __restrict__ meanb,
    const uint4* __restrict__ Wfrag,
    const float* __restrict__ bias, const float* __restrict__ g,
    const float* __restrict__ bt, void* __restrict__ outp, int n,
    int aggN0, int aggN1, int gemmR0, int aggBlocks) {
    constexpr int NT = NOUT / 16;
    constexpr int CT = NT / 4;
    constexpr int SROW = 33;
    __shared__ __align__(16) uint4 Abuf[32 * SROW];
    __shared__ float lnbuf[2][4][32];
    int tid = threadIdx.x;
    int lane = tid & 63;

    if ((int)blockIdx.x < aggBlocks) {
        int node = aggN0 + blockIdx.x * 4 + (tid >> 6);
        if (node < aggN1)
            agg_node((const uint4*)Ah, offs, srcs, invc, (uint4*)meanb, node, lane);
        return;
    }

    int w = tid >> 6;
    int q = lane >> 4, m = lane & 15;
    int rowbase = gemmR0 + ((int)blockIdx.x - aggBlocks) * 32;

    f32x4 acc[2][CT];
#pragma unroll
    for (int i = 0; i < 2; i++)
#pragma unroll
        for (int t = 0; t < CT; t++) acc[i][t] = (f32x4)0.f;

    union U { uint4 u; bf16x8 b; };
    U a2[2], breg[3][CT];

    auto stage = [&](const unsigned short* A) {
        const uint4* Ag = (const uint4*)A + (size_t)rowbase * 32;
        uint4 v[4];
#pragma unroll
        for (int j = 0; j < 4; j++) {
            int c = j * 256 + tid;
            int row = c >> 5;
            v[j] = (rowbase + row < n) ? Ag[c] : make_uint4(0u, 0u, 0u, 0u);
        }
#pragma unroll
        for (int j = 0; j < 4; j++) {
            int c = j * 256 + tid;
            int row = c >> 5, kc = c & 31;
            Abuf[row * SROW + kc] = v[j];
        }
    };
    auto loadB = [&](int p, U* br) {
#pragma unroll
        for (int t = 0; t < CT; t++)
            br[t].u = Wfrag[(size_t)(p * NT + w * CT + t) * 64 + lane];
    };

    stage(meanb);
    loadB(0, breg[0]);
    loadB(1, breg[1]);
    __syncthreads();

#pragma unroll
    for (int ph = 0; ph < 2; ph++) {
        if (ph == 1) {
            __syncthreads();
            stage(Ah);
            __syncthreads();
        }
#pragma unroll
        for (int pp = 0; pp < 8; pp++) {
            int p = ph * 8 + pp;
            if (p + 2 < 16) loadB(p + 2, breg[(p + 2) % 3]);
#pragma unroll
            for (int i = 0; i < 2; i++)
                a2[i].u = Abuf[(i * 16 + m) * SROW + pp * 4 + q];
#pragma unroll
            for (int i = 0; i < 2; i++)
#pragma unroll
                for (int t = 0; t < CT; t++)
                    acc[i][t] = __builtin_amdgcn_mfma_f32_16x16x32_bf16(
                        a2[i].b, breg[p % 3][t].b, acc[i][t], 0, 0, 0);
        }
    }

    int col0 = w * CT * 16;
    float bv[CT], gv[CT], btv[CT];
#pragma unroll
    for (int t = 0; t < CT; t++) {
        int c = col0 + t * 16 + m;
        bv[t] = bias[c]; gv[t] = g[c]; btv[t] = bt[c];
    }
#pragma unroll
    for (int i = 0; i < 2; i++) {
#pragma unroll
        for (int r = 0; r < 4; r++) {
            float s1 = 0.f, s2 = 0.f;
#pragma unroll
            for (int t = 0; t < CT; t++) {
                float v = acc[i][t][r] + bv[t];
                acc[i][t][r] = v;
                s1 += v; s2 += v * v;
            }
#pragma unroll
            for (int o = 1; o < 16; o <<= 1) {
                s1 += __shfl_xor(s1, o);
                s2 += __shfl_xor(s2, o);
            }
            if (m == 0) {
                int row = i * 16 + q * 4 + r;
                lnbuf[0][w][row] = s1;
                lnbuf[1][w][row] = s2;
            }
        }
    }
    __syncthreads();
#pragma unroll
    for (int i = 0; i < 2; i++) {
#pragma unroll
        for (int r = 0; r < 4; r++) {
            int rit = i * 16 + q * 4 + r;
            float ts1 = lnbuf[0][0][rit] + lnbuf[0][1][rit] + lnbuf[0][2][rit] + lnbuf[0][3][rit];
            float ts2 = lnbuf[1][0][rit] + lnbuf[1][1][rit] + lnbuf[1][2][rit] + lnbuf[1][3][rit];
            float mu  = ts1 * (1.0f / NOUT);
            float var = ts2 * (1.0f / NOUT) - mu * mu;
            float rs  = 1.0f / sqrtf(var + 1e-5f);
            int row = rowbase + rit;
            if (row < n) {
#pragma unroll
                for (int t = 0; t < CT; t++) {
                    int c = col0 + t * 16 + m;
                    float y = (acc[i][t][r] - mu) * rs * gv[t] + btv[t];
                    float res = gelu_f(y);
                    if (F32OUT) ((float*)outp)[(size_t)row * NOUT + c] = res;
                    else ((unsigned short*)outp)[(size_t)row * NOUT + c] = f2bf(res);
                }
            }
        }
    }
}

// ---------------- layer-1 MFMA GEMM ----------------

__global__ __launch_bounds__(256) void k_gemm_mfma1(
    const unsigned short* __restrict__ A1, const uint4* __restrict__ Wfrag,
    const float* __restrict__ bias, const float* __restrict__ g,
    const float* __restrict__ bt, unsigned short* __restrict__ outp, int n) {
    constexpr int NT = 16, CT = 4;
    __shared__ float lnbuf[2][4][64];
    int tid = threadIdx.x;
    int w = tid >> 6, lane = tid & 63;
    int q = lane >> 4, m = lane & 15;
    int rowbase = blockIdx.x * 64;

    union U { uint4 u; bf16x8 b; };
    U a[4], b[CT];
#pragma unroll
    for (int i = 0; i < 4; i++) {
        int row = rowbase + i * 16 + m;
        a[i].u = (row < n) ? *(const uint4*)(A1 + (size_t)row * 32 + q * 8)
                           : make_uint4(0u, 0u, 0u, 0u);
    }
#pragma unroll
    for (int t = 0; t < CT; t++)
        b[t].u = Wfrag[(size_t)(w * CT + t) * 64 + lane];

    f32x4 acc[4][CT];
#pragma unroll
    for (int i = 0; i < 4; i++)
#pragma unroll
        for (int t = 0; t < CT; t++)
            acc[i][t] = __builtin_amdgcn_mfma_f32_16x16x32_bf16(
                a[i].b, b[t].b, (f32x4)0.f, 0, 0, 0);

    int col0 = w * CT * 16;
    float bv[CT], gv[CT], btv[CT];
#pragma unroll
    for (int t = 0; t < CT; t++) {
        int c = col0 + t * 16 + m;
        bv[t] = bias[c]; gv[t] = g[c]; btv[t] = bt[c];
    }
#pragma unroll
    for (int i = 0; i < 4; i++) {
#pragma unroll
        for (int r = 0; r < 4; r++) {
            float s1 = 0.f, s2 = 0.f;
#pragma unroll
            for (int t = 0; t < CT; t++) {
                float v = acc[i][t][r] + bv[t];
                acc[i][t][r] = v;
                s1 += v; s2 += v * v;
            }
#pragma unroll
            for (int o = 1; o < 16; o <<= 1) {
                s1 += __shfl_xor(s1, o);
                s2 += __shfl_xor(s2, o);
            }
            if (m == 0) {
                int row = i * 16 + q * 4 + r;
                lnbuf[0][w][row] = s1;
                lnbuf[1][w][row] = s2;
            }
        }
    }
    __syncthreads();
#pragma unroll
    for (int i = 0; i < 4; i++) {
#pragma unroll
        for (int r = 0; r < 4; r++) {
            int rit = i * 16 + q * 4 + r;
            float ts1 = lnbuf[0][0][rit] + lnbuf[0][1][rit] + lnbuf[0][2][rit] + lnbuf[0][3][rit];
            float ts2 = lnbuf[1][0][rit] + lnbuf[1][1][rit] + lnbuf[1][2][rit] + lnbuf[1][3][rit];
            float mu  = ts1 * (1.0f / HID);
            float var = ts2 * (1.0f / HID) - mu * mu;
            float rs  = 1.0f / sqrtf(var + 1e-5f);
            int row = rowbase + rit;
            if (row < n) {
#pragma unroll
                for (int t = 0; t < CT; t++) {
                    int c = col0 + t * 16 + m;
                    float y = (acc[i][t][r] - mu) * rs * gv[t] + btv[t];
                    outp[(size_t)row * HID + c] = f2bf(gelu_f(y));
                }
            }
        }
    }
}

// ---------------- pool ----------------

__global__ __launch_bounds__(1024) void k_pool(const float* __restrict__ h,
                                               const int* __restrict__ boff,
                                               float* __restrict__ out) {
    __shared__ float red[8][128];
    int b = blockIdx.x, tid = threadIdx.x;
    int j = tid & 127, grp = tid >> 7;
    int s0 = boff[b], s1 = boff[b + 1];
    float a0 = 0.f, a1 = 0.f, a2 = 0.f, a3 = 0.f;
    int i = s0 + grp;
    for (; i + 24 < s1; i += 32) {
        a0 += h[(size_t)i * OUTF + j];
        a1 += h[(size_t)(i + 8) * OUTF + j];
        a2 += h[(size_t)(i + 16) * OUTF + j];
        a3 += h[(size_t)(i + 24) * OUTF + j];
    }
    for (; i < s1; i += 8) a0 += h[(size_t)i * OUTF + j];
    red[grp][j] = (a0 + a1) + (a2 + a3);
    __syncthreads();
    if (tid < 128) {
        float s = ((red[0][tid] + red[1][tid]) + (red[2][tid] + red[3][tid]))
                + ((red[4][tid] + red[5][tid]) + (red[6][tid] + red[7][tid]));
        int c = s1 - s0;
        out[b * OUTF + tid] = s / fmaxf((float)c, 1.0f);
    }
}

// ---------------- launch ----------------

extern "C" void kernel_launch(void* const* d_in, const int* in_sizes, int n_in,
                              void* d_out, int out_size, void* d_ws, size_t ws_size,
                              hipStream_t stream) {
    const float* x     = (const float*)d_in[0];
    const int*   ei    = (const int*)d_in[1];
    const int*   src   = ei;
    const int*   dst   = ei + Ee;
    const int*   batch = (const int*)d_in[2];
    const float* Wl1 = (const float*)d_in[3];
    const float* Wr1 = (const float*)d_in[4];
    const float* b1  = (const float*)d_in[5];
    const float* g1  = (const float*)d_in[6];
    const float* bt1 = (const float*)d_in[7];
    const float* Wl2 = (const float*)d_in[8];
    const float* Wr2 = (const float*)d_in[9];
    const float* b2  = (const float*)d_in[10];
    const float* g2  = (const float*)d_in[11];
    const float* bt2 = (const float*)d_in[12];
    const float* Wl3 = (const float*)d_in[13];
    const float* Wr3 = (const float*)d_in[14];
    const float* b3  = (const float*)d_in[15];
    const float* g3  = (const float*)d_in[16];
    const float* bt3 = (const float*)d_in[17];
    const float* Wl4 = (const float*)d_in[18];
    const float* Wr4 = (const float*)d_in[19];
    const float* b4  = (const float*)d_in[20];
    const float* g4  = (const float*)d_in[21];
    const float* bt4 = (const float*)d_in[22];
    float* out = (float*)d_out;

    char* ws = (char*)d_ws;
    size_t off = 0;
    auto alloc = [&](size_t bytes) -> char* {
        char* p = ws + off;
        off = (off + bytes + 255) & ~(size_t)255;
        return p;
    };
    int*   offs    = (int*)alloc((size_t)(Nn + 1) * 4);
    int*   srcs    = (int*)alloc((size_t)Ee * 4);
    float* invc    = (float*)alloc((size_t)Nn * 4);
    int*   boff    = (int*)alloc((size_t)(Bb + 1) * 4);
    unsigned int* pairs = (unsigned int*)alloc((size_t)Ee * 4);
    int*   Gcnt    = (int*)alloc((size_t)SCANN * 4);
    int*   Goff    = (int*)alloc((size_t)SCANN * 4);
    int*   partial = (int*)alloc(256 * 4);
    unsigned short* A1    = (unsigned short*)alloc((size_t)Nn * 32 * 2);
    unsigned short* meanb = (unsigned short*)alloc((size_t)Nn * HID * 2);
    unsigned short* hA    = (unsigned short*)alloc((size_t)Nn * HID * 2);
    unsigned short* hB    = (unsigned short*)alloc((size_t)Nn * HID * 2);
    float* hOut    = (float*)alloc((size_t)Nn * OUTF * 4);
    uint4* W1f     = (uint4*)alloc((size_t)32 * HID * 2);
    uint4* W2f     = (uint4*)alloc((size_t)512 * HID * 2);
    uint4* W3f     = (uint4*)alloc((size_t)512 * HID * 2);
    uint4* W4f     = (uint4*)alloc((size_t)512 * OUTF * 2);

    int nbScan = (SCANN + 255) / 256;
    k_sortA<<<NB1, 256, 0, stream>>>(dst, Gcnt);
    k_gscan_partial<<<nbScan, 256, 0, stream>>>(Gcnt, partial, SCANN);
    k_gscan_mid<<<1, 256, 0, stream>>>(partial, nbScan);
    k_gscan_final<<<nbScan, 256, 0, stream>>>(Gcnt, partial, Goff, SCANN);
    k_sortC<<<NB1, 256, 0, stream>>>(dst, src, Goff, pairs);
    k_sortD<<<NCB, 256, 0, stream>>>(pairs, Goff, offs, srcs, invc);
    k_bsearch<<<1, 256, 0, stream>>>(batch, boff, offs);

    k_prepW1<<<4, 256, 0, stream>>>(Wl1, Wr1, W1f);
    k_prepW<256><<<64, 256, 0, stream>>>(Wl2, Wr2, W2f);
    k_prepW<256><<<64, 256, 0, stream>>>(Wl3, Wr3, W3f);
    k_prepW<128><<<32, 256, 0, stream>>>(Wl4, Wr4, W4f);

    int gb64 = (Nn + 63) / 64;
    // layer 1 (MFMA, K=32)
    k_prep1<<<Nn / 16, 256, 0, stream>>>(x, offs, srcs, invc, A1);
    k_gemm_mfma1<<<gb64, 256, 0, stream>>>(A1, W1f, b1, g1, bt1, hA, Nn);

    // pipeline boundaries and block counts
    const int bnd[5] = {0, S1, S2, S3, Nn};
    auto aggB  = [&](int i) { return (bnd[i + 1] - bnd[i] + 3) / 4; };
    auto gemmB = [&](int i) { return (bnd[i + 1] - bnd[i] + 31) / 32; };

#define LAYER_PIPE(NOUTV, F32V, HIN, WF, BV, GV, BTV, HOUT)                              \
    {                                                                                    \
        k_mix<NOUTV, F32V><<<aggB(0), 256, 0, stream>>>(                                 \
            HIN, offs, srcs, invc, meanb, WF, BV, GV, BTV, HOUT, Nn,                     \
            bnd[0], bnd[1], 0, aggB(0));                                                 \
        for (int c = 1; c < 4; c++)                                                      \
            k_mix<NOUTV, F32V><<<aggB(c) + gemmB(c - 1), 256, 0, stream>>>(              \
                HIN, offs, srcs, invc, meanb, WF, BV, GV, BTV, HOUT, Nn,                 \
                bnd[c], bnd[c + 1], bnd[c - 1], aggB(c));                                \
        k_mix<NOUTV, F32V><<<gemmB(3), 256, 0, stream>>>(                                \
            HIN, offs, srcs, invc, meanb, WF, BV, GV, BTV, HOUT, Nn,                     \
            0, 0, bnd[3], 0);                                                            \
    }

    // layer 2
    LAYER_PIPE(256, false, hA, W2f, b2, g2, bt2, hB)
    // layer 3
    LAYER_PIPE(256, false, hB, W3f, b3, g3, bt3, hA)
    // layer 4
    LAYER_PIPE(128, true,  hA, W4f, b4, g4, bt4, hOut)
#undef LAYER_PIPE

    // pool
    k_pool<<<Bb, 1024, 0, stream>>>(hOut, boff, out);
}

// Round 18
// 456.079 us; speedup vs baseline: 1.2231x; 1.2231x over previous
//
#include <hip/hip_runtime.h>
#include <math.h>

constexpr int Nn   = 50000;
constexpr int Ee   = 800000;
constexpr int Bb   = 128;
constexpr int INF  = 15;
constexpr int HID  = 256;
constexpr int OUTF = 128;

constexpr int NCB   = (Nn + 255) / 256;   // 196 coarse buckets (dst>>8)
constexpr int CHUNK = 4096;
constexpr int NB1   = (Ee + CHUNK - 1) / CHUNK;  // 196 sort blocks
constexpr int SCANN = NCB * NB1;          // 38416

typedef __attribute__((ext_vector_type(8))) __bf16 bf16x8;
typedef __attribute__((ext_vector_type(4))) float  f32x4;

// gelu(v) = 0.5 v (1 + erf(v/sqrt2)); erf via A&S 7.1.26 (max err 1.5e-7, sub-bf16-ulp).
__device__ __forceinline__ float gelu_f(float v) {
    float s = fabsf(v) * 0.7071067811865475f;
    float t = __builtin_amdgcn_rcpf(fmaf(0.3275911f, s, 1.0f));
    float p = fmaf(fmaf(fmaf(fmaf(1.061405429f, t, -1.453152027f),
                             t, 1.421413741f), t, -0.284496736f), t, 0.254829592f) * t;
    float e = __expf(-s * s);
    float er = copysignf(1.0f - p * e, v);
    return 0.5f * v * (1.0f + er);
}

__device__ __forceinline__ unsigned short f2bf(float f) {
    union { float f; unsigned int u; } v; v.f = f;
    unsigned int r = v.u + 0x7fffu + ((v.u >> 16) & 1u);   // RNE
    return (unsigned short)(r >> 16);
}

__device__ __forceinline__ float bflo(unsigned int p) { return __uint_as_float(p << 16); }
__device__ __forceinline__ float bfhi(unsigned int p) { return __uint_as_float(p & 0xffff0000u); }

// ---------------- CSR build: two-level counting sort (LDS atomics only) ----------------

__global__ void k_sortA(const int* __restrict__ dst, int* __restrict__ Gcnt) {
    __shared__ int cnt[NCB];
    int tid = threadIdx.x, blk = blockIdx.x;
    for (int i = tid; i < NCB; i += 256) cnt[i] = 0;
    __syncthreads();
    int base = blk * CHUNK;
    for (int i = 0; i < CHUNK; i += 256) {
        int e = base + i + tid;
        if (e < Ee) atomicAdd(&cnt[dst[e] >> 8], 1);
    }
    __syncthreads();
    for (int i = tid; i < NCB; i += 256) Gcnt[i * NB1 + blk] = cnt[i];
}

__global__ void k_gscan_partial(const int* __restrict__ in, int* __restrict__ partial, int n) {
    __shared__ int s[256];
    int tid = threadIdx.x, i = blockIdx.x * 256 + tid;
    s[tid] = (i < n) ? in[i] : 0;
    __syncthreads();
    for (int off = 128; off; off >>= 1) {
        if (tid < off) s[tid] += s[tid + off];
        __syncthreads();
    }
    if (tid == 0) partial[blockIdx.x] = s[0];
}

__global__ void k_gscan_mid(int* __restrict__ partial, int nb) {
    __shared__ int s[256];
    int tid = threadIdx.x;
    int v = (tid < nb) ? partial[tid] : 0;
    s[tid] = v;
    __syncthreads();
    for (int off = 1; off < 256; off <<= 1) {
        int t = (tid >= off) ? s[tid - off] : 0;
        __syncthreads();
        s[tid] += t;
        __syncthreads();
    }
    if (tid < nb) partial[tid] = s[tid] - v;
}

__global__ void k_gscan_final(const int* __restrict__ in, const int* __restrict__ partial,
                              int* __restrict__ out, int n) {
    __shared__ int s[256];
    int tid = threadIdx.x, i = blockIdx.x * 256 + tid;
    int v = (i < n) ? in[i] : 0;
    s[tid] = v;
    __syncthreads();
    for (int off = 1; off < 256; off <<= 1) {
        int t = (tid >= off) ? s[tid - off] : 0;
        __syncthreads();
        s[tid] += t;
        __syncthreads();
    }
    if (i < n) out[i] = s[tid] - v + partial[blockIdx.x];
}

__global__ void k_sortC(const int* __restrict__ dst, const int* __restrict__ srcv,
                        const int* __restrict__ Goff, unsigned int* __restrict__ pairs) {
    __shared__ int cur[NCB];
    int tid = threadIdx.x, blk = blockIdx.x;
    for (int i = tid; i < NCB; i += 256) cur[i] = Goff[i * NB1 + blk];
    __syncthreads();
    int base = blk * CHUNK;
    for (int i = 0; i < CHUNK; i += 256) {
        int e = base + i + tid;
        if (e < Ee) {
            int d = dst[e];
            int p = atomicAdd(&cur[d >> 8], 1);
            pairs[p] = ((unsigned int)(d & 255) << 16) | (unsigned int)srcv[e];
        }
    }
}

__global__ void k_sortD(const unsigned int* __restrict__ pairs, const int* __restrict__ Goff,
                        int* __restrict__ offs, int* __restrict__ srcs, float* __restrict__ invc) {
    __shared__ int fcnt[256];
    __shared__ int fbase[256];
    __shared__ int s[256];
    int tid = threadIdx.x, cb = blockIdx.x;
    int cbase = Goff[cb * NB1];
    int cend = (cb + 1 < NCB) ? Goff[(cb + 1) * NB1] : Ee;
    fcnt[tid] = 0;
    __syncthreads();
    for (int e = cbase + tid; e < cend; e += 256)
        atomicAdd(&fcnt[pairs[e] >> 16], 1);
    __syncthreads();
    int v = fcnt[tid];
    s[tid] = v;
    __syncthreads();
    for (int off = 1; off < 256; off <<= 1) {
        int t = (tid >= off) ? s[tid - off] : 0;
        __syncthreads();
        s[tid] += t;
        __syncthreads();
    }
    fbase[tid] = cbase + s[tid] - v;
    int node = cb * 256 + tid;
    if (node < Nn) {
        offs[node] = fbase[tid];
        invc[node] = 1.0f / (float)(v > 1 ? v : 1);
    }
    __syncthreads();
    fcnt[tid] = fbase[tid];
    __syncthreads();
    for (int e = cbase + tid; e < cend; e += 256) {
        unsigned int pv = pairs[e];
        int p = atomicAdd(&fcnt[pv >> 16], 1);
        srcs[p] = (int)(pv & 0xFFFFu);
    }
}

__global__ void k_bsearch(const int* __restrict__ batch, int* __restrict__ boff,
                          int* __restrict__ offs) {
    int b = threadIdx.x;
    if (b <= Bb) {
        int lo = 0, hi = Nn;
        while (lo < hi) {
            int mid = (lo + hi) >> 1;
            if (batch[mid] < b) lo = mid + 1; else hi = mid;
        }
        boff[b] = lo;
    }
    if (b == 0) offs[Nn] = Ee;
}

// ---------------- weight prep (layers 2-4): fragment-ordered bf16 ----------------

template <int NOUT>
__global__ void k_prepW(const float* __restrict__ Wl, const float* __restrict__ Wr,
                        uint4* __restrict__ outw) {
    constexpr int NT = NOUT / 16;
    int G = blockIdx.x * 256 + threadIdx.x;
    int per = 2 * NT * 64;
    int S = G / per, rem = G % per;
    int lane = rem & 63, sT = rem >> 6;
    int s = sT / NT, T = sT % NT;
    int q = lane >> 4, m = lane & 15;
    int k0 = S * 64 + s * 32 + q * 8;
    int nc = T * 16 + m;
    union { uint4 u; unsigned short h[8]; } pk;
#pragma unroll
    for (int j = 0; j < 8; j++) {
        int kk = k0 + j;
        float wv = (kk < 256) ? Wl[kk * NOUT + nc] : Wr[(kk - 256) * NOUT + nc];
        pk.h[j] = f2bf(wv);
    }
    outw[G] = pk.u;
}

// layer 1: [Wl1(15) | 0 | Wr1(15) | 0] -> K=32 fragment order, NT=16 tiles
__global__ void k_prepW1(const float* __restrict__ Wl, const float* __restrict__ Wr,
                         uint4* __restrict__ outw) {
    int G = blockIdx.x * 256 + threadIdx.x;   // 0..1023
    int T = G >> 6, lane = G & 63;
    int q = lane >> 4, m = lane & 15;
    int nc = T * 16 + m;
    union { uint4 u; unsigned short h[8]; } pk;
#pragma unroll
    for (int j = 0; j < 8; j++) {
        int k = q * 8 + j;
        float wv;
        if (k < 15)       wv = Wl[k * HID + nc];
        else if (k == 15) wv = 0.0f;
        else if (k < 31)  wv = Wr[(k - 16) * HID + nc];
        else              wv = 0.0f;
        pk.h[j] = f2bf(wv);
    }
    outw[G] = pk.u;
}

// ---------------- layer-1 A build ----------------

__global__ void k_prep1(const float* __restrict__ x, const int* __restrict__ offs,
                        const int* __restrict__ srcs, const float* __restrict__ invc,
                        unsigned short* __restrict__ A1) {
    int node = blockIdx.x * 16 + (threadIdx.x >> 4);
    int f = threadIdx.x & 15;
    int s0 = offs[node], s1 = offs[node + 1];
    float acc = 0.0f;
    for (int i = s0; i < s1; i++) {
        int s = srcs[i];
        if (f < 15) acc += x[s * INF + f];
    }
    unsigned short mv = (f < 15) ? f2bf(acc * invc[node]) : (unsigned short)0;
    unsigned short xv = (f < 15) ? f2bf(x[(size_t)node * INF + f]) : (unsigned short)0;
    A1[(size_t)node * 32 + f] = mv;
    A1[(size_t)node * 32 + 16 + f] = xv;
}

// ---------------- aggregation (256-d bf16), 16 edges in flight ----------------

__device__ __forceinline__ void acc8(float* a, uint4 v) {
    a[0] += bflo(v.x); a[1] += bfhi(v.x);
    a[2] += bflo(v.y); a[3] += bfhi(v.y);
    a[4] += bflo(v.z); a[5] += bfhi(v.z);
    a[6] += bflo(v.w); a[7] += bfhi(v.w);
}

__global__ void k_agg256_bf(const uint4* __restrict__ h4, const int* __restrict__ offs,
                            const int* __restrict__ srcs, const float* __restrict__ invc,
                            uint4* __restrict__ mean4) {
    int node = blockIdx.x * 4 + (threadIdx.x >> 6);
    int lane = threadIdx.x & 63;
    int sub = lane >> 5, q = lane & 31;
    int s0 = offs[node], s1 = offs[node + 1];
    int deg = s1 - s0;
    int dcap = deg < 64 ? deg : 64;
    int myidx = (lane < deg) ? srcs[s0 + lane] : 0;
    float a[8] = {};
    int i = 0;
    for (; i + 16 <= dcap; i += 16) {
        int sA = __shfl(myidx, i + sub);
        int sB = __shfl(myidx, i + 2 + sub);
        int sC = __shfl(myidx, i + 4 + sub);
        int sD = __shfl(myidx, i + 6 + sub);
        int sE = __shfl(myidx, i + 8 + sub);
        int sF = __shfl(myidx, i + 10 + sub);
        int sG = __shfl(myidx, i + 12 + sub);
        int sH = __shfl(myidx, i + 14 + sub);
        uint4 vA = h4[(size_t)sA * 32 + q];
        uint4 vB = h4[(size_t)sB * 32 + q];
        uint4 vC = h4[(size_t)sC * 32 + q];
        uint4 vD = h4[(size_t)sD * 32 + q];
        uint4 vE = h4[(size_t)sE * 32 + q];
        uint4 vF = h4[(size_t)sF * 32 + q];
        uint4 vG = h4[(size_t)sG * 32 + q];
        uint4 vH = h4[(size_t)sH * 32 + q];
        acc8(a, vA); acc8(a, vB); acc8(a, vC); acc8(a, vD);
        acc8(a, vE); acc8(a, vF); acc8(a, vG); acc8(a, vH);
    }
    if (i + 8 <= dcap) {
        int sA = __shfl(myidx, i + sub);
        int sB = __shfl(myidx, i + 2 + sub);
        int sC = __shfl(myidx, i + 4 + sub);
        int sD = __shfl(myidx, i + 6 + sub);
        uint4 vA = h4[(size_t)sA * 32 + q];
        uint4 vB = h4[(size_t)sB * 32 + q];
        uint4 vC = h4[(size_t)sC * 32 + q];
        uint4 vD = h4[(size_t)sD * 32 + q];
        acc8(a, vA); acc8(a, vB); acc8(a, vC); acc8(a, vD);
        i += 8;
    }
    if (i + 4 <= dcap) {
        int sA = __shfl(myidx, i + sub);
        int sB = __shfl(myidx, i + 2 + sub);
        uint4 vA = h4[(size_t)sA * 32 + q];
        uint4 vB = h4[(size_t)sB * 32 + q];
        acc8(a, vA); acc8(a, vB);
        i += 4;
    }
    if (i + 2 <= dcap) {
        int sA = __shfl(myidx, i + sub);
        uint4 vA = h4[(size_t)sA * 32 + q];
        acc8(a, vA);
        i += 2;
    }
    if (i < dcap && sub == 0) {
        int sA = __shfl(myidx, i);
        uint4 vA = h4[(size_t)sA * 32 + q];
        acc8(a, vA);
    }
    for (int j = 64; j + 1 < deg; j += 2) {
        int s = srcs[s0 + j + sub];
        uint4 v = h4[(size_t)s * 32 + q];
        acc8(a, v);
    }
    if (deg > 64 && ((deg - 64) & 1) && sub == 0) {
        int s = srcs[s1 - 1];
        uint4 v = h4[(size_t)s * 32 + q];
        acc8(a, v);
    }
#pragma unroll
    for (int j = 0; j < 8; j++) a[j] += __shfl_xor(a[j], 32);
    if (sub == 0) {
        float ic = invc[node];
        uint4 o;
        o.x = (unsigned int)f2bf(a[0] * ic) | ((unsigned int)f2bf(a[1] * ic) << 16);
        o.y = (unsigned int)f2bf(a[2] * ic) | ((unsigned int)f2bf(a[3] * ic) << 16);
        o.z = (unsigned int)f2bf(a[4] * ic) | ((unsigned int)f2bf(a[5] * ic) << 16);
        o.w = (unsigned int)f2bf(a[6] * ic) | ((unsigned int)f2bf(a[7] * ic) << 16);
        mean4[(size_t)node * 32 + q] = o;
    }
}

// ---------------- MFMA GEMM v5 (R14-proven): M=32 tile, LDS A, rolling-3 B ----------------

template <int NOUT, bool F32OUT>
__global__ __launch_bounds__(256) void k_gemm_mfma(
    const unsigned short* __restrict__ Am,
    const unsigned short* __restrict__ Ah,
    const uint4* __restrict__ Wfrag,
    const float* __restrict__ bias, const float* __restrict__ g,
    const float* __restrict__ bt, void* __restrict__ outp, int n) {
    constexpr int NT = NOUT / 16;
    constexpr int CT = NT / 4;
    constexpr int SROW = 33;                     // uint4 per LDS row
    __shared__ __align__(16) uint4 Abuf[32 * SROW];
    __shared__ float lnbuf[2][4][32];
    int tid = threadIdx.x;
    int w = tid >> 6, lane = tid & 63;
    int q = lane >> 4, m = lane & 15;
    int rowbase = blockIdx.x * 32;

    f32x4 acc[2][CT];
#pragma unroll
    for (int i = 0; i < 2; i++)
#pragma unroll
        for (int t = 0; t < CT; t++) acc[i][t] = (f32x4)0.f;

    union U { uint4 u; bf16x8 b; };
    U a[2], breg[3][CT];

    auto stage = [&](const unsigned short* A) {
        const uint4* Ag = (const uint4*)A + (size_t)rowbase * 32;
        uint4 v[4];
#pragma unroll
        for (int j = 0; j < 4; j++) {
            int c = j * 256 + tid;
            int row = c >> 5;
            v[j] = (rowbase + row < n) ? Ag[c] : make_uint4(0u, 0u, 0u, 0u);
        }
#pragma unroll
        for (int j = 0; j < 4; j++) {
            int c = j * 256 + tid;
            int row = c >> 5, kc = c & 31;
            Abuf[row * SROW + kc] = v[j];
        }
    };
    auto loadB = [&](int p, U* br) {
#pragma unroll
        for (int t = 0; t < CT; t++)
            br[t].u = Wfrag[(size_t)(p * NT + w * CT + t) * 64 + lane];
    };

    stage(Am);
    loadB(0, breg[0]);
    loadB(1, breg[1]);
    __syncthreads();

#pragma unroll
    for (int ph = 0; ph < 2; ph++) {
        if (ph == 1) {
            __syncthreads();     // all waves done reading mean tiles
            stage(Ah);
            __syncthreads();
        }
#pragma unroll
        for (int pp = 0; pp < 8; pp++) {
            int p = ph * 8 + pp;
            if (p + 2 < 16) loadB(p + 2, breg[(p + 2) % 3]);
#pragma unroll
            for (int i = 0; i < 2; i++)
                a[i].u = Abuf[(i * 16 + m) * SROW + pp * 4 + q];
#pragma unroll
            for (int i = 0; i < 2; i++)
#pragma unroll
                for (int t = 0; t < CT; t++)
                    acc[i][t] = __builtin_amdgcn_mfma_f32_16x16x32_bf16(
                        a[i].b, breg[p % 3][t].b, acc[i][t], 0, 0, 0);
        }
    }

    int col0 = w * CT * 16;
    float bv[CT], gv[CT], btv[CT];
#pragma unroll
    for (int t = 0; t < CT; t++) {
        int c = col0 + t * 16 + m;
        bv[t] = bias[c]; gv[t] = g[c]; btv[t] = bt[c];
    }
#pragma unroll
    for (int i = 0; i < 2; i++) {
#pragma unroll
        for (int r = 0; r < 4; r++) {
            float s1 = 0.f, s2 = 0.f;
#pragma unroll
            for (int t = 0; t < CT; t++) {
                float v = acc[i][t][r] + bv[t];
                acc[i][t][r] = v;
                s1 += v; s2 += v * v;
            }
#pragma unroll
            for (int o = 1; o < 16; o <<= 1) {
                s1 += __shfl_xor(s1, o);
                s2 += __shfl_xor(s2, o);
            }
            if (m == 0) {
                int row = i * 16 + q * 4 + r;
                lnbuf[0][w][row] = s1;
                lnbuf[1][w][row] = s2;
            }
        }
    }
    __syncthreads();
#pragma unroll
    for (int i = 0; i < 2; i++) {
#pragma unroll
        for (int r = 0; r < 4; r++) {
            int rit = i * 16 + q * 4 + r;
            float ts1 = lnbuf[0][0][rit] + lnbuf[0][1][rit] + lnbuf[0][2][rit] + lnbuf[0][3][rit];
            float ts2 = lnbuf[1][0][rit] + lnbuf[1][1][rit] + lnbuf[1][2][rit] + lnbuf[1][3][rit];
            float mu  = ts1 * (1.0f / NOUT);
            float var = ts2 * (1.0f / NOUT) - mu * mu;
            float rs  = 1.0f / sqrtf(var + 1e-5f);
            int row = rowbase + rit;
            if (row < n) {
#pragma unroll
                for (int t = 0; t < CT; t++) {
                    int c = col0 + t * 16 + m;
                    float y = (acc[i][t][r] - mu) * rs * gv[t] + btv[t];
                    float res = gelu_f(y);
                    if (F32OUT) ((float*)outp)[(size_t)row * NOUT + c] = res;
                    else ((unsigned short*)outp)[(size_t)row * NOUT + c] = f2bf(res);
                }
            }
        }
    }
}

// ---------------- layer-1 MFMA GEMM: single K=32 step on A1, LN+GELU ----------------

__global__ __launch_bounds__(256) void k_gemm_mfma1(
    const unsigned short* __restrict__ A1, const uint4* __restrict__ Wfrag,
    const float* __restrict__ bias, const float* __restrict__ g,
    const float* __restrict__ bt, unsigned short* __restrict__ outp, int n) {
    constexpr int NT = 16, CT = 4;
    __shared__ float lnbuf[2][4][64];
    int tid = threadIdx.x;
    int w = tid >> 6, lane = tid & 63;
    int q = lane >> 4, m = lane & 15;
    int rowbase = blockIdx.x * 64;

    union U { uint4 u; bf16x8 b; };
    U a[4], b[CT];
#pragma unroll
    for (int i = 0; i < 4; i++) {
        int row = rowbase + i * 16 + m;
        a[i].u = (row < n) ? *(const uint4*)(A1 + (size_t)row * 32 + q * 8)
                           : make_uint4(0u, 0u, 0u, 0u);
    }
#pragma unroll
    for (int t = 0; t < CT; t++)
        b[t].u = Wfrag[(size_t)(w * CT + t) * 64 + lane];

    f32x4 acc[4][CT];
#pragma unroll
    for (int i = 0; i < 4; i++)
#pragma unroll
        for (int t = 0; t < CT; t++)
            acc[i][t] = __builtin_amdgcn_mfma_f32_16x16x32_bf16(
                a[i].b, b[t].b, (f32x4)0.f, 0, 0, 0);

    int col0 = w * CT * 16;
    float bv[CT], gv[CT], btv[CT];
#pragma unroll
    for (int t = 0; t < CT; t++) {
        int c = col0 + t * 16 + m;
        bv[t] = bias[c]; gv[t] = g[c]; btv[t] = bt[c];
    }
#pragma unroll
    for (int i = 0; i < 4; i++) {
#pragma unroll
        for (int r = 0; r < 4; r++) {
            float s1 = 0.f, s2 = 0.f;
#pragma unroll
            for (int t = 0; t < CT; t++) {
                float v = acc[i][t][r] + bv[t];
                acc[i][t][r] = v;
                s1 += v; s2 += v * v;
            }
#pragma unroll
            for (int o = 1; o < 16; o <<= 1) {
                s1 += __shfl_xor(s1, o);
                s2 += __shfl_xor(s2, o);
            }
            if (m == 0) {
                int row = i * 16 + q * 4 + r;
                lnbuf[0][w][row] = s1;
                lnbuf[1][w][row] = s2;
            }
        }
    }
    __syncthreads();
#pragma unroll
    for (int i = 0; i < 4; i++) {
#pragma unroll
        for (int r = 0; r < 4; r++) {
            int rit = i * 16 + q * 4 + r;
            float ts1 = lnbuf[0][0][rit] + lnbuf[0][1][rit] + lnbuf[0][2][rit] + lnbuf[0][3][rit];
            float ts2 = lnbuf[1][0][rit] + lnbuf[1][1][rit] + lnbuf[1][2][rit] + lnbuf[1][3][rit];
            float mu  = ts1 * (1.0f / HID);
            float var = ts2 * (1.0f / HID) - mu * mu;
            float rs  = 1.0f / sqrtf(var + 1e-5f);
            int row = rowbase + rit;
            if (row < n) {
#pragma unroll
                for (int t = 0; t < CT; t++) {
                    int c = col0 + t * 16 + m;
                    float y = (acc[i][t][r] - mu) * rs * gv[t] + btv[t];
                    outp[(size_t)row * HID + c] = f2bf(gelu_f(y));
                }
            }
        }
    }
}

// ---------------- pool ----------------

__global__ __launch_bounds__(1024) void k_pool(const float* __restrict__ h,
                                               const int* __restrict__ boff,
                                               float* __restrict__ out) {
    __shared__ float red[8][128];
    int b = blockIdx.x, tid = threadIdx.x;
    int j = tid & 127, grp = tid >> 7;
    int s0 = boff[b], s1 = boff[b + 1];
    float a0 = 0.f, a1 = 0.f, a2 = 0.f, a3 = 0.f;
    int i = s0 + grp;
    for (; i + 24 < s1; i += 32) {
        a0 += h[(size_t)i * OUTF + j];
        a1 += h[(size_t)(i + 8) * OUTF + j];
        a2 += h[(size_t)(i + 16) * OUTF + j];
        a3 += h[(size_t)(i + 24) * OUTF + j];
    }
    for (; i < s1; i += 8) a0 += h[(size_t)i * OUTF + j];
    red[grp][j] = (a0 + a1) + (a2 + a3);
    __syncthreads();
    if (tid < 128) {
        float s = ((red[0][tid] + red[1][tid]) + (red[2][tid] + red[3][tid]))
                + ((red[4][tid] + red[5][tid]) + (red[6][tid] + red[7][tid]));
        int c = s1 - s0;
        out[b * OUTF + tid] = s / fmaxf((float)c, 1.0f);
    }
}

// ---------------- launch ----------------

extern "C" void kernel_launch(void* const* d_in, const int* in_sizes, int n_in,
                              void* d_out, int out_size, void* d_ws, size_t ws_size,
                              hipStream_t stream) {
    const float* x     = (const float*)d_in[0];
    const int*   ei    = (const int*)d_in[1];
    const int*   src   = ei;
    const int*   dst   = ei + Ee;
    const int*   batch = (const int*)d_in[2];
    const float* Wl1 = (const float*)d_in[3];
    const float* Wr1 = (const float*)d_in[4];
    const float* b1  = (const float*)d_in[5];
    const float* g1  = (const float*)d_in[6];
    const float* bt1 = (const float*)d_in[7];
    const float* Wl2 = (const float*)d_in[8];
    const float* Wr2 = (const float*)d_in[9];
    const float* b2  = (const float*)d_in[10];
    const float* g2  = (const float*)d_in[11];
    const float* bt2 = (const float*)d_in[12];
    const float* Wl3 = (const float*)d_in[13];
    const float* Wr3 = (const float*)d_in[14];
    const float* b3  = (const float*)d_in[15];
    const float* g3  = (const float*)d_in[16];
    const float* bt3 = (const float*)d_in[17];
    const float* Wl4 = (const float*)d_in[18];
    const float* Wr4 = (const float*)d_in[19];
    const float* b4  = (const float*)d_in[20];
    const float* g4  = (const float*)d_in[21];
    const float* bt4 = (const float*)d_in[22];
    float* out = (float*)d_out;

    char* ws = (char*)d_ws;
    size_t off = 0;
    auto alloc = [&](size_t bytes) -> char* {
        char* p = ws + off;
        off = (off + bytes + 255) & ~(size_t)255;
        return p;
    };
    int*   offs    = (int*)alloc((size_t)(Nn + 1) * 4);
    int*   srcs    = (int*)alloc((size_t)Ee * 4);
    float* invc    = (float*)alloc((size_t)Nn * 4);
    int*   boff    = (int*)alloc((size_t)(Bb + 1) * 4);
    unsigned int* pairs = (unsigned int*)alloc((size_t)Ee * 4);
    int*   Gcnt    = (int*)alloc((size_t)SCANN * 4);
    int*   Goff    = (int*)alloc((size_t)SCANN * 4);
    int*   partial = (int*)alloc(256 * 4);
    unsigned short* A1    = (unsigned short*)alloc((size_t)Nn * 32 * 2);
    unsigned short* meanb = (unsigned short*)alloc((size_t)Nn * HID * 2);
    unsigned short* hA    = (unsigned short*)alloc((size_t)Nn * HID * 2);
    unsigned short* hB    = (unsigned short*)alloc((size_t)Nn * HID * 2);
    float* hOut    = (float*)alloc((size_t)Nn * OUTF * 4);
    uint4* W1f     = (uint4*)alloc((size_t)32 * HID * 2);
    uint4* W2f     = (uint4*)alloc((size_t)512 * HID * 2);
    uint4* W3f     = (uint4*)alloc((size_t)512 * HID * 2);
    uint4* W4f     = (uint4*)alloc((size_t)512 * OUTF * 2);

    int nbScan = (SCANN + 255) / 256;
    k_sortA<<<NB1, 256, 0, stream>>>(dst, Gcnt);
    k_gscan_partial<<<nbScan, 256, 0, stream>>>(Gcnt, partial, SCANN);
    k_gscan_mid<<<1, 256, 0, stream>>>(partial, nbScan);
    k_gscan_final<<<nbScan, 256, 0, stream>>>(Gcnt, partial, Goff, SCANN);
    k_sortC<<<NB1, 256, 0, stream>>>(dst, src, Goff, pairs);
    k_sortD<<<NCB, 256, 0, stream>>>(pairs, Goff, offs, srcs, invc);
    k_bsearch<<<1, 256, 0, stream>>>(batch, boff, offs);

    k_prepW1<<<4, 256, 0, stream>>>(Wl1, Wr1, W1f);
    k_prepW<256><<<64, 256, 0, stream>>>(Wl2, Wr2, W2f);
    k_prepW<256><<<64, 256, 0, stream>>>(Wl3, Wr3, W3f);
    k_prepW<128><<<32, 256, 0, stream>>>(Wl4, Wr4, W4f);

    int gb64 = (Nn + 63) / 64;
    int gb32 = (Nn + 31) / 32;
    // layer 1 (MFMA, K=32)
    k_prep1<<<Nn / 16, 256, 0, stream>>>(x, offs, srcs, invc, A1);
    k_gemm_mfma1<<<gb64, 256, 0, stream>>>(A1, W1f, b1, g1, bt1, hA, Nn);
    // layer 2
    k_agg256_bf<<<Nn / 4, 256, 0, stream>>>((const uint4*)hA, offs, srcs, invc, (uint4*)meanb);
    k_gemm_mfma<256, false><<<gb32, 256, 0, stream>>>(meanb, hA, W2f, b2, g2, bt2, hB, Nn);
    // layer 3
    k_agg256_bf<<<Nn / 4, 256, 0, stream>>>((const uint4*)hB, offs, srcs, invc, (uint4*)meanb);
    k_gemm_mfma<256, false><<<gb32, 256, 0, stream>>>(meanb, hB, W3f, b3, g3, bt3, hA, Nn);
    // layer 4
    k_agg256_bf<<<Nn / 4, 256, 0, stream>>>((const uint4*)hA, offs, srcs, invc, (uint4*)meanb);
    k_gemm_mfma<128, true><<<gb32, 256, 0, stream>>>(meanb, hA, W4f, b4, g4, bt4, hOut, Nn);
    // pool
    k_pool<<<Bb, 1024, 0, stream>>>(hOut, boff, out);
}